// Round 2
// baseline (652.530 us; speedup 1.0000x reference)
//
#include <hip/hip_runtime.h>
#include <stdint.h>

typedef unsigned short u16;
typedef __attribute__((ext_vector_type(8))) short bf16x8;
typedef __attribute__((ext_vector_type(4))) float f32x4;

__device__ __forceinline__ u16 f2bf(float f) {
  unsigned int u = __float_as_uint(f);
  u += 0x7fffu + ((u >> 16) & 1u);
  return (u16)(u >> 16);
}
__device__ __forceinline__ float bf2f(u16 h) {
  return __uint_as_float(((unsigned int)h) << 16);
}

__device__ __forceinline__ void gld16(const void* g, void* l) {
  __builtin_amdgcn_global_load_lds(
      (const __attribute__((address_space(1))) unsigned int*)g,
      (__attribute__((address_space(3))) unsigned int*)l,
      16, 0, 0);
}

// ---------------- fp32 -> bf16 (plain) ----------------
__global__ __launch_bounds__(256) void cvt_f32_bf16(const float* __restrict__ in,
                                                    u16* __restrict__ out, int n4) {
  int stride = gridDim.x * blockDim.x;
  for (int i = blockIdx.x * blockDim.x + threadIdx.x; i < n4; i += stride) {
    float4 v = reinterpret_cast<const float4*>(in)[i];
    ushort4 o;
    o.x = f2bf(v.x); o.y = f2bf(v.y); o.z = f2bf(v.z); o.w = f2bf(v.w);
    reinterpret_cast<ushort4*>(out)[i] = o;
  }
}

// ---------------- fp32 -> bf16 hi/lo split ----------------
__global__ __launch_bounds__(256) void split_f32_bf16(const float* __restrict__ in,
                                                      u16* __restrict__ hi,
                                                      u16* __restrict__ lo, int n4) {
  int stride = gridDim.x * blockDim.x;
  for (int i = blockIdx.x * blockDim.x + threadIdx.x; i < n4; i += stride) {
    float4 v = reinterpret_cast<const float4*>(in)[i];
    ushort4 h, l;
    h.x = f2bf(v.x); l.x = f2bf(v.x - bf2f(h.x));
    h.y = f2bf(v.y); l.y = f2bf(v.y - bf2f(h.y));
    h.z = f2bf(v.z); l.z = f2bf(v.z - bf2f(h.z));
    h.w = f2bf(v.w); l.w = f2bf(v.w - bf2f(h.w));
    reinterpret_cast<ushort4*>(hi)[i] = h;
    reinterpret_cast<ushort4*>(lo)[i] = l;
  }
}

// stage one 128x32 tile (row-major, K=1024 source) into linear LDS
__device__ __forceinline__ void stage_tile(const u16* __restrict__ M, int r0, int k0,
                                           u16* S, int wid, int lane) {
#pragma unroll
  for (int it = 0; it < 2; ++it) {
    int row = wid * 32 + it * 16 + (lane >> 2);
    int col = k0 + (lane & 3) * 8;
    gld16(M + (size_t)(r0 + row) * 1024 + col, S + wid * 1024 + it * 512);
  }
}

// ---------------- Q/K projection, 3-pass split-precision ----------------
// C[R][e] = sum_k x[R][k] * w[e][k]  computed as xh*wh + xh*wl + xl*wh
// epilogue splits result into hi/lo bf16 planes in attention layout [b][h][m][j]
__global__ __launch_bounds__(256) void proj_qk(
    const u16* __restrict__ xh, const u16* __restrict__ xl,
    const u16* __restrict__ wqh, const u16* __restrict__ wql,
    const u16* __restrict__ wkh, const u16* __restrict__ wkl,
    const float* __restrict__ bq, const float* __restrict__ bk,
    u16* __restrict__ Qh, u16* __restrict__ Ql,
    u16* __restrict__ Kh, u16* __restrict__ Kl) {
  const int mat = blockIdx.z;
  const u16* __restrict__ wh = mat ? wkh : wqh;
  const u16* __restrict__ wl = mat ? wkl : wql;
  const float* __restrict__ bias = mat ? bk : bq;
  const int m0 = blockIdx.x * 128;
  const int n0 = blockIdx.y * 128;

  __shared__ __align__(16) u16 Ah[128 * 32];
  __shared__ __align__(16) u16 Al[128 * 32];
  __shared__ __align__(16) u16 Bh[128 * 32];
  __shared__ __align__(16) u16 Bl[128 * 32];

  const int tid = threadIdx.x;
  const int lane = tid & 63;
  const int wid = tid >> 6;
  const int wr = wid >> 1, wc = wid & 1;
  const int qd = lane >> 4, lm = lane & 15;

  f32x4 acc[4][4];
#pragma unroll
  for (int i = 0; i < 4; ++i)
#pragma unroll
    for (int j = 0; j < 4; ++j) acc[i][j] = (f32x4){0.f, 0.f, 0.f, 0.f};

  stage_tile(xh, m0, 0, Ah, wid, lane);
  stage_tile(xl, m0, 0, Al, wid, lane);
  stage_tile(wh, n0, 0, Bh, wid, lane);
  stage_tile(wl, n0, 0, Bl, wid, lane);

  for (int kt = 0; kt < 32; ++kt) {
    __syncthreads();
    bf16x8 ahf[4], alf[4], bhf[4], blf[4];
#pragma unroll
    for (int i = 0; i < 4; ++i) {
      ahf[i] = *reinterpret_cast<const bf16x8*>(Ah + (wr * 64 + i * 16 + lm) * 32 + qd * 8);
      alf[i] = *reinterpret_cast<const bf16x8*>(Al + (wr * 64 + i * 16 + lm) * 32 + qd * 8);
    }
#pragma unroll
    for (int j = 0; j < 4; ++j) {
      bhf[j] = *reinterpret_cast<const bf16x8*>(Bh + (wc * 64 + j * 16 + lm) * 32 + qd * 8);
      blf[j] = *reinterpret_cast<const bf16x8*>(Bl + (wc * 64 + j * 16 + lm) * 32 + qd * 8);
    }
#pragma unroll
    for (int i = 0; i < 4; ++i)
#pragma unroll
      for (int j = 0; j < 4; ++j) {
        acc[i][j] = __builtin_amdgcn_mfma_f32_16x16x32_bf16(ahf[i], bhf[j], acc[i][j], 0, 0, 0);
        acc[i][j] = __builtin_amdgcn_mfma_f32_16x16x32_bf16(ahf[i], blf[j], acc[i][j], 0, 0, 0);
        acc[i][j] = __builtin_amdgcn_mfma_f32_16x16x32_bf16(alf[i], bhf[j], acc[i][j], 0, 0, 0);
      }
    __syncthreads();
    if (kt + 1 < 32) {
      stage_tile(xh, m0, (kt + 1) * 32, Ah, wid, lane);
      stage_tile(xl, m0, (kt + 1) * 32, Al, wid, lane);
      stage_tile(wh, n0, (kt + 1) * 32, Bh, wid, lane);
      stage_tile(wl, n0, (kt + 1) * 32, Bl, wid, lane);
    }
  }

#pragma unroll
  for (int i = 0; i < 4; ++i) {
#pragma unroll
    for (int r = 0; r < 4; ++r) {
      int R = m0 + wr * 64 + i * 16 + qd * 4 + r;
      int b = R >> 12, n = R & 4095;
      int c = n >> 10, s = n & 1023;
      int rb = s & 3, t = s >> 2;
      int m = c * 256 + t;
#pragma unroll
      for (int j = 0; j < 4; ++j) {
        int e = n0 + wc * 64 + j * 16 + lm;
        int head = e >> 6, jj = e & 63;
        int h = rb * 16 + head;
        float val = acc[i][j][r] + bias[e];
        u16 h16 = f2bf(val);
        u16 l16 = f2bf(val - bf2f(h16));
        size_t idx = (((size_t)b * 64 + h) * 1024 + m) * 64 + jj;
        if (mat == 0) { Qh[idx] = h16; Ql[idx] = l16; }
        else          { Kh[idx] = h16; Kl[idx] = l16; }
      }
    }
  }
}

// ---------------- V projection (plain bf16), output transposed Vt[b][h][j][m] -----
__global__ __launch_bounds__(256) void proj_v(
    const u16* __restrict__ xh, const u16* __restrict__ wvb,
    const float* __restrict__ bv, u16* __restrict__ Vt) {
  const int m0 = blockIdx.x * 128;
  const int n0 = blockIdx.y * 128;

  __shared__ __align__(16) u16 As[128 * 32];
  __shared__ __align__(16) u16 Bs[128 * 32];

  const int tid = threadIdx.x;
  const int lane = tid & 63;
  const int wid = tid >> 6;
  const int wr = wid >> 1, wc = wid & 1;
  const int qd = lane >> 4, lm = lane & 15;

  f32x4 acc[4][4];
#pragma unroll
  for (int i = 0; i < 4; ++i)
#pragma unroll
    for (int j = 0; j < 4; ++j) acc[i][j] = (f32x4){0.f, 0.f, 0.f, 0.f};

  stage_tile(xh, m0, 0, As, wid, lane);
  stage_tile(wvb, n0, 0, Bs, wid, lane);

  for (int kt = 0; kt < 32; ++kt) {
    __syncthreads();
    bf16x8 af[4], bfr[4];
#pragma unroll
    for (int i = 0; i < 4; ++i)
      af[i] = *reinterpret_cast<const bf16x8*>(As + (wr * 64 + i * 16 + lm) * 32 + qd * 8);
#pragma unroll
    for (int j = 0; j < 4; ++j)
      bfr[j] = *reinterpret_cast<const bf16x8*>(Bs + (wc * 64 + j * 16 + lm) * 32 + qd * 8);
#pragma unroll
    for (int i = 0; i < 4; ++i)
#pragma unroll
      for (int j = 0; j < 4; ++j)
        acc[i][j] = __builtin_amdgcn_mfma_f32_16x16x32_bf16(af[i], bfr[j], acc[i][j], 0, 0, 0);
    __syncthreads();
    if (kt + 1 < 32) {
      stage_tile(xh, m0, (kt + 1) * 32, As, wid, lane);
      stage_tile(wvb, n0, (kt + 1) * 32, Bs, wid, lane);
    }
  }

#pragma unroll
  for (int i = 0; i < 4; ++i) {
#pragma unroll
    for (int r = 0; r < 4; ++r) {
      int R = m0 + wr * 64 + i * 16 + qd * 4 + r;
      int b = R >> 12, n = R & 4095;
      int c = n >> 10, s = n & 1023;
      int rb = s & 3, t = s >> 2;
      int m = c * 256 + t;
#pragma unroll
      for (int j = 0; j < 4; ++j) {
        int e = n0 + wc * 64 + j * 16 + lm;
        int head = e >> 6, jj = e & 63;
        int h = rb * 16 + head;
        float val = acc[i][j][r] + bv[e];
        Vt[(((size_t)b * 64 + h) * 64 + jj) * 1024 + m] = f2bf(val);
      }
    }
  }
}

// ---------------- flash attention with 3-pass split-precision QK^T ----------------
__global__ __launch_bounds__(256) void attn_kernel(
    const u16* __restrict__ Qh, const u16* __restrict__ Ql,
    const u16* __restrict__ Kh, const u16* __restrict__ Kl,
    const u16* __restrict__ Vt, u16* __restrict__ Of) {
  const int bh = blockIdx.x;
  const int b = bh >> 6, h = bh & 63;
  const int m0 = blockIdx.y * 128;
  const int tid = threadIdx.x, lane = tid & 63, wv = tid >> 6;
  const int qd = lane >> 4, lm = lane & 15;

  __shared__ __align__(16) u16 Ksh[64 * 72];
  __shared__ __align__(16) u16 Ksl[64 * 72];
  __shared__ __align__(16) u16 Vs[64 * 72];
  __shared__ __align__(16) u16 Ps[128 * 72];

  const size_t hb = ((size_t)(b * 64 + h));
  const u16* __restrict__ Qhp = Qh + hb * 1024 * 64;
  const u16* __restrict__ Qlp = Ql + hb * 1024 * 64;
  const u16* __restrict__ Khp = Kh + hb * 1024 * 64;
  const u16* __restrict__ Klp = Kl + hb * 1024 * 64;
  const u16* __restrict__ Vhp = Vt + hb * 64 * 1024;

  bf16x8 qfh[2][2], qfl[2][2];
#pragma unroll
  for (int im = 0; im < 2; ++im)
#pragma unroll
    for (int ks = 0; ks < 2; ++ks) {
      size_t off = (size_t)(m0 + wv * 32 + im * 16 + lm) * 64 + ks * 32 + qd * 8;
      qfh[im][ks] = *reinterpret_cast<const bf16x8*>(Qhp + off);
      qfl[im][ks] = *reinterpret_cast<const bf16x8*>(Qlp + off);
    }

  f32x4 oa[2][4];
  float mr[2][4], lr[2][4];
#pragma unroll
  for (int im = 0; im < 2; ++im)
#pragma unroll
    for (int r = 0; r < 4; ++r) { mr[im][r] = -3.0e38f; lr[im][r] = 0.f; }
#pragma unroll
  for (int im = 0; im < 2; ++im)
#pragma unroll
    for (int jf = 0; jf < 4; ++jf) oa[im][jf] = (f32x4){0.f, 0.f, 0.f, 0.f};

  for (int kc = 0; kc < 16; ++kc) {
#pragma unroll
    for (int it = 0; it < 2; ++it) {
      int idx = it * 256 + tid;
      int rr = idx >> 3, pp = idx & 7;
      uint4 a = *reinterpret_cast<const uint4*>(Khp + (size_t)(kc * 64 + rr) * 64 + pp * 8);
      *reinterpret_cast<uint4*>(&Ksh[rr * 72 + pp * 8]) = a;
      uint4 c = *reinterpret_cast<const uint4*>(Klp + (size_t)(kc * 64 + rr) * 64 + pp * 8);
      *reinterpret_cast<uint4*>(&Ksl[rr * 72 + pp * 8]) = c;
      uint4 v = *reinterpret_cast<const uint4*>(Vhp + (size_t)rr * 1024 + kc * 64 + pp * 8);
      *reinterpret_cast<uint4*>(&Vs[rr * 72 + pp * 8]) = v;
    }
    __syncthreads();

    f32x4 sc[2][4];
#pragma unroll
    for (int im = 0; im < 2; ++im)
#pragma unroll
      for (int nf = 0; nf < 4; ++nf) sc[im][nf] = (f32x4){0.f, 0.f, 0.f, 0.f};
#pragma unroll
    for (int ks = 0; ks < 2; ++ks) {
      bf16x8 kfh[4], kfl[4];
#pragma unroll
      for (int nf = 0; nf < 4; ++nf) {
        kfh[nf] = *reinterpret_cast<const bf16x8*>(&Ksh[(nf * 16 + lm) * 72 + ks * 32 + qd * 8]);
        kfl[nf] = *reinterpret_cast<const bf16x8*>(&Ksl[(nf * 16 + lm) * 72 + ks * 32 + qd * 8]);
      }
#pragma unroll
      for (int im = 0; im < 2; ++im)
#pragma unroll
        for (int nf = 0; nf < 4; ++nf) {
          sc[im][nf] = __builtin_amdgcn_mfma_f32_16x16x32_bf16(qfh[im][ks], kfh[nf], sc[im][nf], 0, 0, 0);
          sc[im][nf] = __builtin_amdgcn_mfma_f32_16x16x32_bf16(qfh[im][ks], kfl[nf], sc[im][nf], 0, 0, 0);
          sc[im][nf] = __builtin_amdgcn_mfma_f32_16x16x32_bf16(qfl[im][ks], kfh[nf], sc[im][nf], 0, 0, 0);
        }
    }

    // scale by sqrt(dh)=8 (exact in fp32), then online softmax
#pragma unroll
    for (int im = 0; im < 2; ++im) {
#pragma unroll
      for (int r = 0; r < 4; ++r) {
#pragma unroll
        for (int nf = 0; nf < 4; ++nf) sc[im][nf][r] *= 8.0f;
        float pm = fmaxf(fmaxf(sc[im][0][r], sc[im][1][r]), fmaxf(sc[im][2][r], sc[im][3][r]));
#pragma unroll
        for (int d = 1; d < 16; d <<= 1) pm = fmaxf(pm, __shfl_xor(pm, d));
        float mn = fmaxf(mr[im][r], pm);
        float corr = __expf(mr[im][r] - mn);
        float ps = 0.f;
#pragma unroll
        for (int nf = 0; nf < 4; ++nf) {
          float p = __expf(sc[im][nf][r] - mn);
          sc[im][nf][r] = p;
          ps += p;
        }
#pragma unroll
        for (int d = 1; d < 16; d <<= 1) ps += __shfl_xor(ps, d);
        lr[im][r] = lr[im][r] * corr + ps;
        mr[im][r] = mn;
#pragma unroll
        for (int jf = 0; jf < 4; ++jf) oa[im][jf][r] *= corr;
#pragma unroll
        for (int nf = 0; nf < 4; ++nf)
          Ps[(wv * 32 + im * 16 + qd * 4 + r) * 72 + nf * 16 + lm] = f2bf(sc[im][nf][r]);
      }
    }

#pragma unroll
    for (int ks = 0; ks < 2; ++ks) {
      bf16x8 pf[2], vf[4];
#pragma unroll
      for (int im = 0; im < 2; ++im)
        pf[im] = *reinterpret_cast<const bf16x8*>(&Ps[(wv * 32 + im * 16 + lm) * 72 + ks * 32 + qd * 8]);
#pragma unroll
      for (int jf = 0; jf < 4; ++jf)
        vf[jf] = *reinterpret_cast<const bf16x8*>(&Vs[(jf * 16 + lm) * 72 + ks * 32 + qd * 8]);
#pragma unroll
      for (int im = 0; im < 2; ++im)
#pragma unroll
        for (int jf = 0; jf < 4; ++jf)
          oa[im][jf] = __builtin_amdgcn_mfma_f32_16x16x32_bf16(pf[im], vf[jf], oa[im][jf], 0, 0, 0);
    }
    __syncthreads();
  }

  const int rb = h >> 4, head = h & 15;
#pragma unroll
  for (int im = 0; im < 2; ++im) {
#pragma unroll
    for (int r = 0; r < 4; ++r) {
      int mq = m0 + wv * 32 + im * 16 + qd * 4 + r;
      float inv = 1.0f / lr[im][r];
      int c = mq >> 8, t = mq & 255;
      int s = t * 4 + rb;
      int n = c * 1024 + s;
#pragma unroll
      for (int jf = 0; jf < 4; ++jf) {
        int j = jf * 16 + lm;
        int f = head * 64 + j;
        Of[((size_t)b * 4096 + n) * 1024 + f] = f2bf(oa[im][jf][r] * inv);
      }
    }
  }
}

// ---------------- output projection GEMM ----------------
__global__ __launch_bounds__(256) void out_gemm(
    const u16* __restrict__ Of, const u16* __restrict__ wob,
    const float* __restrict__ bo, float* __restrict__ out) {
  const int m0 = blockIdx.x * 128;
  const int n0 = blockIdx.y * 128;

  __shared__ __align__(16) u16 As[128 * 32];
  __shared__ __align__(16) u16 Bs[128 * 32];

  const int tid = threadIdx.x;
  const int lane = tid & 63;
  const int wid = tid >> 6;
  const int wr = wid >> 1, wc = wid & 1;
  const int qd = lane >> 4, lm = lane & 15;

  f32x4 acc[4][4];
#pragma unroll
  for (int i = 0; i < 4; ++i)
#pragma unroll
    for (int j = 0; j < 4; ++j) acc[i][j] = (f32x4){0.f, 0.f, 0.f, 0.f};

  stage_tile(Of, m0, 0, As, wid, lane);
  stage_tile(wob, n0, 0, Bs, wid, lane);

  for (int kt = 0; kt < 32; ++kt) {
    __syncthreads();
    bf16x8 af[4], bfr[4];
#pragma unroll
    for (int i = 0; i < 4; ++i)
      af[i] = *reinterpret_cast<const bf16x8*>(As + (wr * 64 + i * 16 + lm) * 32 + qd * 8);
#pragma unroll
    for (int j = 0; j < 4; ++j)
      bfr[j] = *reinterpret_cast<const bf16x8*>(Bs + (wc * 64 + j * 16 + lm) * 32 + qd * 8);
#pragma unroll
    for (int i = 0; i < 4; ++i)
#pragma unroll
      for (int j = 0; j < 4; ++j)
        acc[i][j] = __builtin_amdgcn_mfma_f32_16x16x32_bf16(af[i], bfr[j], acc[i][j], 0, 0, 0);
    __syncthreads();
    if (kt + 1 < 32) {
      stage_tile(Of, m0, (kt + 1) * 32, As, wid, lane);
      stage_tile(wob, n0, (kt + 1) * 32, Bs, wid, lane);
    }
  }

#pragma unroll
  for (int i = 0; i < 4; ++i) {
#pragma unroll
    for (int r = 0; r < 4; ++r) {
      int R = m0 + wr * 64 + i * 16 + qd * 4 + r;
#pragma unroll
      for (int j = 0; j < 4; ++j) {
        int e = n0 + wc * 64 + j * 16 + lm;
        out[(size_t)R * 1024 + e] = acc[i][j][r] + bo[e];
      }
    }
  }
}

// ---------------- launch ----------------
extern "C" void kernel_launch(void* const* d_in, const int* in_sizes, int n_in,
                              void* d_out, int out_size, void* d_ws, size_t ws_size,
                              hipStream_t stream) {
  const float* x  = (const float*)d_in[0];
  const float* wq = (const float*)d_in[1];
  const float* bq = (const float*)d_in[2];
  const float* wk = (const float*)d_in[3];
  const float* bk = (const float*)d_in[4];
  const float* wv = (const float*)d_in[5];
  const float* bv = (const float*)d_in[6];
  const float* wo = (const float*)d_in[7];
  const float* bo = (const float*)d_in[8];
  float* out = (float*)d_out;

  char* ws = (char*)d_ws;
  u16* xh  = (u16*)(ws + 0);            // 33,554,432 B
  u16* xl  = (u16*)(ws + 33554432);     // 33,554,432 B  (reused as Of after projections)
  u16* wqh = (u16*)(ws + 67108864);     //  2,097,152 B each
  u16* wql = (u16*)(ws + 69206016);
  u16* wkh = (u16*)(ws + 71303168);
  u16* wkl = (u16*)(ws + 73400320);
  u16* wvb = (u16*)(ws + 75497472);
  u16* wob = (u16*)(ws + 77594624);
  u16* Qhb = (u16*)(ws + 79691776);     // 33,554,432 B  [b][h][m][j]
  u16* Qlb = (u16*)(ws + 113246208);
  u16* Khb = (u16*)(ws + 146800640);
  u16* Klb = (u16*)(ws + 180355072);
  u16* Vtb = (u16*)(ws + 213909504);    // 33,554,432 B  [b][h][j][m]
  u16* Ofb = xl;                        // alias: xl dead after proj_qk

  split_f32_bf16<<<4096, 256, 0, stream>>>(x,  xh,  xl,  16777216 / 4);
  split_f32_bf16<<<1024, 256, 0, stream>>>(wq, wqh, wql, 1048576 / 4);
  split_f32_bf16<<<1024, 256, 0, stream>>>(wk, wkh, wkl, 1048576 / 4);
  cvt_f32_bf16<<<1024, 256, 0, stream>>>(wv, wvb, 1048576 / 4);
  cvt_f32_bf16<<<1024, 256, 0, stream>>>(wo, wob, 1048576 / 4);

  proj_qk<<<dim3(128, 8, 2), 256, 0, stream>>>(xh, xl, wqh, wql, wkh, wkl, bq, bk,
                                               Qhb, Qlb, Khb, Klb);
  proj_v<<<dim3(128, 8), 256, 0, stream>>>(xh, wvb, bv, Vtb);
  attn_kernel<<<dim3(256, 8), 256, 0, stream>>>(Qhb, Qlb, Khb, Klb, Vtb, Ofb);
  out_gemm<<<dim3(128, 8), 256, 0, stream>>>(Ofb, wob, bo, out);
}

// Round 4
// 483.019 us; speedup vs baseline: 1.3509x; 1.3509x over previous
//
#include <hip/hip_runtime.h>
#include <stdint.h>

typedef unsigned short u16;
typedef _Float16 f16;
typedef __attribute__((ext_vector_type(8))) _Float16 f16x8;
typedef __attribute__((ext_vector_type(2))) _Float16 f16x2;
typedef __attribute__((ext_vector_type(4))) float f32x4;

__device__ __forceinline__ float exp2fast(float x) {
  return __builtin_amdgcn_exp2f(x);   // v_exp_f32: 2^x
}

__device__ __forceinline__ f32x4 mfma16(f16x8 a, f16x8 b, f32x4 c) {
  return __builtin_amdgcn_mfma_f32_16x16x32_f16(a, b, c, 0, 0, 0);
}

__device__ __forceinline__ u16 f2h(float f) {
  return __builtin_bit_cast(u16, (f16)f);
}

__device__ __forceinline__ void gld16(const void* g, void* l) {
  __builtin_amdgcn_global_load_lds(
      (const __attribute__((address_space(1))) unsigned int*)g,
      (__attribute__((address_space(3))) unsigned int*)l,
      16, 0, 0);
}

// ---------------- fp32 -> fp16 (plain) ----------------
__global__ __launch_bounds__(256) void cvt_f32_f16(const float* __restrict__ in,
                                                   u16* __restrict__ out, int n4) {
  int stride = gridDim.x * blockDim.x;
  for (int i = blockIdx.x * blockDim.x + threadIdx.x; i < n4; i += stride) {
    float4 v = reinterpret_cast<const float4*>(in)[i];
    ushort4 o;
    o.x = f2h(v.x); o.y = f2h(v.y); o.z = f2h(v.z); o.w = f2h(v.w);
    reinterpret_cast<ushort4*>(out)[i] = o;
  }
}

// ---------------- fp32 -> fp16 hi/lo split ----------------
__global__ __launch_bounds__(256) void split_f32_f16(const float* __restrict__ in,
                                                     u16* __restrict__ hi,
                                                     u16* __restrict__ lo, int n4) {
  int stride = gridDim.x * blockDim.x;
  for (int i = blockIdx.x * blockDim.x + threadIdx.x; i < n4; i += stride) {
    float4 v = reinterpret_cast<const float4*>(in)[i];
    ushort4 h, l;
    f16 a;
    a = (f16)v.x; h.x = __builtin_bit_cast(u16, a); l.x = f2h(v.x - (float)a);
    a = (f16)v.y; h.y = __builtin_bit_cast(u16, a); l.y = f2h(v.y - (float)a);
    a = (f16)v.z; h.z = __builtin_bit_cast(u16, a); l.z = f2h(v.z - (float)a);
    a = (f16)v.w; h.w = __builtin_bit_cast(u16, a); l.w = f2h(v.w - (float)a);
    reinterpret_cast<ushort4*>(hi)[i] = h;
    reinterpret_cast<ushort4*>(lo)[i] = l;
  }
}

// stage one 128x32 tile (row-major, K=1024 source) into linear LDS
__device__ __forceinline__ void stage_tile(const u16* __restrict__ M, int r0, int k0,
                                           u16* S, int wid, int lane) {
#pragma unroll
  for (int it = 0; it < 2; ++it) {
    int row = wid * 32 + it * 16 + (lane >> 2);
    int col = k0 + (lane & 3) * 8;
    gld16(M + (size_t)(r0 + row) * 1024 + col, S + wid * 1024 + it * 512);
  }
}

// ---------------- Q/K projection, 2-pass split-x fp16 ----------------
// C[R][e] = sum_k x[R][k]*w[e][k] computed as xh*w + xl*w; output fp16
// Q gets folded scale 8*log2(e); layout [b][h][m][j]
__global__ __launch_bounds__(256) void proj_qk(
    const u16* __restrict__ xh, const u16* __restrict__ xl,
    const u16* __restrict__ wqh, const u16* __restrict__ wkh,
    const float* __restrict__ bq, const float* __restrict__ bk,
    u16* __restrict__ Qf, u16* __restrict__ Kf) {
  const int mat = blockIdx.z;
  const u16* __restrict__ w = mat ? wkh : wqh;
  const float* __restrict__ bias = mat ? bk : bq;
  const int m0 = blockIdx.x * 128;
  const int n0 = blockIdx.y * 128;

  __shared__ __align__(16) u16 Ah[128 * 32];
  __shared__ __align__(16) u16 Al[128 * 32];
  __shared__ __align__(16) u16 Bs[128 * 32];

  const int tid = threadIdx.x;
  const int lane = tid & 63;
  const int wid = tid >> 6;
  const int wr = wid >> 1, wc = wid & 1;
  const int qd = lane >> 4, lm = lane & 15;

  f32x4 acc[4][4];
#pragma unroll
  for (int i = 0; i < 4; ++i)
#pragma unroll
    for (int j = 0; j < 4; ++j) acc[i][j] = (f32x4){0.f, 0.f, 0.f, 0.f};

  stage_tile(xh, m0, 0, Ah, wid, lane);
  stage_tile(xl, m0, 0, Al, wid, lane);
  stage_tile(w, n0, 0, Bs, wid, lane);

  for (int kt = 0; kt < 32; ++kt) {
    __syncthreads();
    f16x8 ahf[4], alf[4], bf[4];
#pragma unroll
    for (int i = 0; i < 4; ++i) {
      ahf[i] = *reinterpret_cast<const f16x8*>(Ah + (wr * 64 + i * 16 + lm) * 32 + qd * 8);
      alf[i] = *reinterpret_cast<const f16x8*>(Al + (wr * 64 + i * 16 + lm) * 32 + qd * 8);
    }
#pragma unroll
    for (int j = 0; j < 4; ++j)
      bf[j] = *reinterpret_cast<const f16x8*>(Bs + (wc * 64 + j * 16 + lm) * 32 + qd * 8);
#pragma unroll
    for (int i = 0; i < 4; ++i)
#pragma unroll
      for (int j = 0; j < 4; ++j) {
        acc[i][j] = mfma16(ahf[i], bf[j], acc[i][j]);
        acc[i][j] = mfma16(alf[i], bf[j], acc[i][j]);
      }
    __syncthreads();
    if (kt + 1 < 32) {
      stage_tile(xh, m0, (kt + 1) * 32, Ah, wid, lane);
      stage_tile(xl, m0, (kt + 1) * 32, Al, wid, lane);
      stage_tile(w, n0, (kt + 1) * 32, Bs, wid, lane);
    }
  }

  const float scale = mat ? 1.0f : 11.5415603f;  // 8*log2(e) folded into Q
#pragma unroll
  for (int i = 0; i < 4; ++i) {
#pragma unroll
    for (int r = 0; r < 4; ++r) {
      int R = m0 + wr * 64 + i * 16 + qd * 4 + r;
      int b = R >> 12, n = R & 4095;
      int c = n >> 10, s = n & 1023;
      int rb = s & 3, t = s >> 2;
      int m = c * 256 + t;
#pragma unroll
      for (int j = 0; j < 4; ++j) {
        int e = n0 + wc * 64 + j * 16 + lm;
        int head = e >> 6, jj = e & 63;
        int h = rb * 16 + head;
        float val = (acc[i][j][r] + bias[e]) * scale;
        size_t idx = (((size_t)b * 64 + h) * 1024 + m) * 64 + jj;
        if (mat == 0) Qf[idx] = f2h(val);
        else          Kf[idx] = f2h(val);
      }
    }
  }
}

// ---------------- V projection (single-pass fp16), output Vt[b][h][j][m] -----
__global__ __launch_bounds__(256) void proj_v(
    const u16* __restrict__ xh, const u16* __restrict__ wvh,
    const float* __restrict__ bv, u16* __restrict__ Vt) {
  const int m0 = blockIdx.x * 128;
  const int n0 = blockIdx.y * 128;

  __shared__ __align__(16) u16 As[128 * 32];
  __shared__ __align__(16) u16 Bs[128 * 32];

  const int tid = threadIdx.x;
  const int lane = tid & 63;
  const int wid = tid >> 6;
  const int wr = wid >> 1, wc = wid & 1;
  const int qd = lane >> 4, lm = lane & 15;

  f32x4 acc[4][4];
#pragma unroll
  for (int i = 0; i < 4; ++i)
#pragma unroll
    for (int j = 0; j < 4; ++j) acc[i][j] = (f32x4){0.f, 0.f, 0.f, 0.f};

  stage_tile(xh, m0, 0, As, wid, lane);
  stage_tile(wvh, n0, 0, Bs, wid, lane);

  for (int kt = 0; kt < 32; ++kt) {
    __syncthreads();
    f16x8 af[4], bf[4];
#pragma unroll
    for (int i = 0; i < 4; ++i)
      af[i] = *reinterpret_cast<const f16x8*>(As + (wr * 64 + i * 16 + lm) * 32 + qd * 8);
#pragma unroll
    for (int j = 0; j < 4; ++j)
      bf[j] = *reinterpret_cast<const f16x8*>(Bs + (wc * 64 + j * 16 + lm) * 32 + qd * 8);
#pragma unroll
    for (int i = 0; i < 4; ++i)
#pragma unroll
      for (int j = 0; j < 4; ++j)
        acc[i][j] = mfma16(af[i], bf[j], acc[i][j]);
    __syncthreads();
    if (kt + 1 < 32) {
      stage_tile(xh, m0, (kt + 1) * 32, As, wid, lane);
      stage_tile(wvh, n0, (kt + 1) * 32, Bs, wid, lane);
    }
  }

#pragma unroll
  for (int i = 0; i < 4; ++i) {
#pragma unroll
    for (int r = 0; r < 4; ++r) {
      int R = m0 + wr * 64 + i * 16 + qd * 4 + r;
      int b = R >> 12, n = R & 4095;
      int c = n >> 10, s = n & 1023;
      int rb = s & 3, t = s >> 2;
      int m = c * 256 + t;
#pragma unroll
      for (int j = 0; j < 4; ++j) {
        int e = n0 + wc * 64 + j * 16 + lm;
        int head = e >> 6, jj = e & 63;
        int h = rb * 16 + head;
        Vt[(((size_t)b * 64 + h) * 64 + jj) * 1024 + m] = f2h(acc[i][j][r] + bv[e]);
      }
    }
  }
}

// swizzled LDS fragment read: row-major [64][64] fp16, 16B-granule XOR swizzle
__device__ __forceinline__ f16x8 lds_frag(const u16* base, int row, int blk) {
  return *reinterpret_cast<const f16x8*>(base + row * 64 + ((blk ^ (row & 7)) << 3));
}

// stage 64x64 fp16 K chunk + V chunk into swizzled LDS via global_load_lds
__device__ __forceinline__ void stage_kv(const u16* __restrict__ Kh,
                                         const u16* __restrict__ Vh, int kc,
                                         u16* KsB, u16* VsB, int wv, int lane) {
  const int l8 = lane >> 3, sl = lane & 7;
  const int rb = wv * 16;
#pragma unroll
  for (int it = 0; it < 2; ++it) {
    int row = rb + it * 8 + l8;
    int gsl = sl ^ l8;  // inverse-swizzled global granule
    gld16(Kh + (size_t)(kc * 64 + row) * 64 + gsl * 8, KsB + (rb + it * 8) * 64);
    gld16(Vh + (size_t)row * 1024 + kc * 64 + gsl * 8, VsB + (rb + it * 8) * 64);
  }
}

// ---------------- flash attention, swapped-QK, in-register P, fp16 ----------------
__global__ __launch_bounds__(256) void attn_kernel(
    const u16* __restrict__ Qf, const u16* __restrict__ Kf,
    const u16* __restrict__ Vt, u16* __restrict__ Of) {
  const int m0 = blockIdx.x * 128;
  const int bh = blockIdx.y;
  const int b = bh >> 6, h = bh & 63;
  const int tid = threadIdx.x, lane = tid & 63, wv = tid >> 6;
  const int qd = lane >> 4, lm = lane & 15;

  __shared__ __align__(16) u16 Ks[2][64 * 64];
  __shared__ __align__(16) u16 Vs[2][64 * 64];

  const size_t hb = (size_t)(b * 64 + h);
  const u16* __restrict__ Qh = Qf + hb * 65536;
  const u16* __restrict__ Kh = Kf + hb * 65536;
  const u16* __restrict__ Vh = Vt + hb * 65536;

  // Q fragments (B-operand: q-row = lm)
  f16x8 qf[2][2];
#pragma unroll
  for (int im = 0; im < 2; ++im)
#pragma unroll
    for (int ks = 0; ks < 2; ++ks)
      qf[im][ks] = *reinterpret_cast<const f16x8*>(
          Qh + (size_t)(m0 + wv * 32 + im * 16 + lm) * 64 + ks * 32 + qd * 8);

  f32x4 oa[2][4];
  float mrow[2] = {-1e30f, -1e30f};
  float lrow[2] = {0.f, 0.f};
#pragma unroll
  for (int im = 0; im < 2; ++im)
#pragma unroll
    for (int jf = 0; jf < 4; ++jf) oa[im][jf] = (f32x4){0.f, 0.f, 0.f, 0.f};

  stage_kv(Kh, Vh, 0, &Ks[0][0], &Vs[0][0], wv, lane);

  for (int kc = 0; kc < 16; ++kc) {
    const int buf = kc & 1;
    __syncthreads();  // drains staging of buf (vmcnt0 before barrier)
    if (kc + 1 < 16) stage_kv(Kh, Vh, kc + 1, &Ks[buf ^ 1][0], &Vs[buf ^ 1][0], wv, lane);

    // swapped QK^T: sc[im][nf] rows = k-local (16nf+4qd+r), cols = q (lm)
    f32x4 sc[2][4];
#pragma unroll
    for (int im = 0; im < 2; ++im)
#pragma unroll
      for (int nf = 0; nf < 4; ++nf) sc[im][nf] = (f32x4){0.f, 0.f, 0.f, 0.f};
#pragma unroll
    for (int ks = 0; ks < 2; ++ks) {
      f16x8 kfr[4];
#pragma unroll
      for (int nf = 0; nf < 4; ++nf)
        kfr[nf] = lds_frag(&Ks[buf][0], nf * 16 + lm, ks * 4 + qd);
#pragma unroll
      for (int im = 0; im < 2; ++im)
#pragma unroll
        for (int nf = 0; nf < 4; ++nf)
          sc[im][nf] = mfma16(kfr[nf], qf[im][ks], sc[im][nf]);
    }

    // online softmax in log2 domain; each lane owns q-row lm (per im)
    unsigned int pk[2][8];
    float corr[2];
#pragma unroll
    for (int im = 0; im < 2; ++im) {
      float pm = sc[im][0][0];
#pragma unroll
      for (int nf = 0; nf < 4; ++nf)
#pragma unroll
        for (int r = 0; r < 4; ++r) pm = fmaxf(pm, sc[im][nf][r]);
      pm = fmaxf(pm, __shfl_xor(pm, 16));
      pm = fmaxf(pm, __shfl_xor(pm, 32));
      float mn = fmaxf(mrow[im], pm);
      corr[im] = exp2fast(mrow[im] - mn);
      mrow[im] = mn;
      float s = 0.f;
#pragma unroll
      for (int nf = 0; nf < 4; ++nf) {
        float p0 = exp2fast(sc[im][nf][0] - mn);
        float p1 = exp2fast(sc[im][nf][1] - mn);
        float p2 = exp2fast(sc[im][nf][2] - mn);
        float p3 = exp2fast(sc[im][nf][3] - mn);
        s += (p0 + p1) + (p2 + p3);
        pk[im][2 * nf + 0] = __builtin_bit_cast(unsigned int, __builtin_amdgcn_cvt_pkrtz(p0, p1));
        pk[im][2 * nf + 1] = __builtin_bit_cast(unsigned int, __builtin_amdgcn_cvt_pkrtz(p2, p3));
      }
      s += __shfl_xor(s, 16);
      s += __shfl_xor(s, 32);
      lrow[im] = lrow[im] * corr[im] + s;
    }

    // rescale O by corr (broadcast per accumulator row)
#pragma unroll
    for (int im = 0; im < 2; ++im)
#pragma unroll
      for (int r = 0; r < 4; ++r) {
        float cb = __shfl(corr[im], qd * 4 + r);
#pragma unroll
        for (int jf = 0; jf < 4; ++jf) oa[im][jf][r] *= cb;
      }

    // PV: redistribute P to A-fragment layout via shfl, then MFMA
#pragma unroll
    for (int ks = 0; ks < 2; ++ks) {
      f16x8 vfr[4];
#pragma unroll
      for (int jf = 0; jf < 4; ++jf)
        vfr[jf] = lds_frag(&Vs[buf][0], jf * 16 + lm, ks * 4 + qd);
#pragma unroll
      for (int im = 0; im < 2; ++im) {
        union { unsigned int w[4]; f16x8 hv; } pa;
#pragma unroll
        for (int w = 0; w < 4; ++w) {
          int srcl = (((2 * qd + (w >> 1)) & 3) << 4) + lm;
          unsigned int a0 = __shfl(pk[im][2 * (2 * ks + 0) + (w & 1)], srcl);
          unsigned int a1 = __shfl(pk[im][2 * (2 * ks + 1) + (w & 1)], srcl);
          pa.w[w] = (qd & 2) ? a1 : a0;
        }
#pragma unroll
        for (int jf = 0; jf < 4; ++jf)
          oa[im][jf] = mfma16(pa.hv, vfr[jf], oa[im][jf]);
      }
    }
  }

  // epilogue: normalize, scatter to Of[b][n][f] (fp16)
  const int rb = h >> 4, head = h & 15;
#pragma unroll
  for (int im = 0; im < 2; ++im) {
#pragma unroll
    for (int r = 0; r < 4; ++r) {
      float lb = __shfl(lrow[im], qd * 4 + r);
      float inv = 1.0f / lb;
      int mq = m0 + wv * 32 + im * 16 + qd * 4 + r;
      int c = mq >> 8, t = mq & 255;
      int s = t * 4 + rb;
      int n = c * 1024 + s;
#pragma unroll
      for (int jf = 0; jf < 4; ++jf) {
        int j = jf * 16 + lm;
        int f = head * 64 + j;
        Of[((size_t)b * 4096 + n) * 1024 + f] = f2h(oa[im][jf][r] * inv);
      }
    }
  }
}

// ---------------- output projection GEMM (fp16 single-pass) ----------------
__global__ __launch_bounds__(256) void out_gemm(
    const u16* __restrict__ Of, const u16* __restrict__ woh,
    const float* __restrict__ bo, float* __restrict__ out) {
  const int m0 = blockIdx.x * 128;
  const int n0 = blockIdx.y * 128;

  __shared__ __align__(16) u16 As[128 * 32];
  __shared__ __align__(16) u16 Bs[128 * 32];

  const int tid = threadIdx.x;
  const int lane = tid & 63;
  const int wid = tid >> 6;
  const int wr = wid >> 1, wc = wid & 1;
  const int qd = lane >> 4, lm = lane & 15;

  f32x4 acc[4][4];
#pragma unroll
  for (int i = 0; i < 4; ++i)
#pragma unroll
    for (int j = 0; j < 4; ++j) acc[i][j] = (f32x4){0.f, 0.f, 0.f, 0.f};

  stage_tile(Of, m0, 0, As, wid, lane);
  stage_tile(woh, n0, 0, Bs, wid, lane);

  for (int kt = 0; kt < 32; ++kt) {
    __syncthreads();
    f16x8 af[4], bf[4];
#pragma unroll
    for (int i = 0; i < 4; ++i)
      af[i] = *reinterpret_cast<const f16x8*>(As + (wr * 64 + i * 16 + lm) * 32 + qd * 8);
#pragma unroll
    for (int j = 0; j < 4; ++j)
      bf[j] = *reinterpret_cast<const f16x8*>(Bs + (wc * 64 + j * 16 + lm) * 32 + qd * 8);
#pragma unroll
    for (int i = 0; i < 4; ++i)
#pragma unroll
      for (int j = 0; j < 4; ++j)
        acc[i][j] = mfma16(af[i], bf[j], acc[i][j]);
    __syncthreads();
    if (kt + 1 < 32) {
      stage_tile(Of, m0, (kt + 1) * 32, As, wid, lane);
      stage_tile(woh, n0, (kt + 1) * 32, Bs, wid, lane);
    }
  }

#pragma unroll
  for (int i = 0; i < 4; ++i) {
#pragma unroll
    for (int r = 0; r < 4; ++r) {
      int R = m0 + wr * 64 + i * 16 + qd * 4 + r;
#pragma unroll
      for (int j = 0; j < 4; ++j) {
        int e = n0 + wc * 64 + j * 16 + lm;
        out[(size_t)R * 1024 + e] = acc[i][j][r] + bo[e];
      }
    }
  }
}

// ---------------- launch ----------------
extern "C" void kernel_launch(void* const* d_in, const int* in_sizes, int n_in,
                              void* d_out, int out_size, void* d_ws, size_t ws_size,
                              hipStream_t stream) {
  const float* x  = (const float*)d_in[0];
  const float* wq = (const float*)d_in[1];
  const float* bq = (const float*)d_in[2];
  const float* wk = (const float*)d_in[3];
  const float* bk = (const float*)d_in[4];
  const float* wv = (const float*)d_in[5];
  const float* bv = (const float*)d_in[6];
  const float* wo = (const float*)d_in[7];
  const float* bo = (const float*)d_in[8];
  float* out = (float*)d_out;

  char* ws = (char*)d_ws;
  u16* xh  = (u16*)(ws + 0);            // 33,554,432 B
  u16* xl  = (u16*)(ws + 33554432);     // 33,554,432 B
  u16* wqh = (u16*)(ws + 67108864);     //  2,097,152 B each
  u16* wkh = (u16*)(ws + 69206016);
  u16* wvh = (u16*)(ws + 71303168);
  u16* woh = (u16*)(ws + 73400320);
  u16* Qfb = (u16*)(ws + 75497472);     // 33,554,432 B  [b][h][m][j] (pre-scaled)
  u16* Kfb = (u16*)(ws + 109051904);    // 33,554,432 B  [b][h][m][j]
  u16* Vtb = (u16*)(ws + 142606336);    // 33,554,432 B  [b][h][j][m]
  u16* Ofb = (u16*)(ws + 176160768);    // 33,554,432 B  [b][n][f]

  split_f32_f16<<<4096, 256, 0, stream>>>(x, xh, xl, 16777216 / 4);
  cvt_f32_f16<<<1024, 256, 0, stream>>>(wq, wqh, 1048576 / 4);
  cvt_f32_f16<<<1024, 256, 0, stream>>>(wk, wkh, 1048576 / 4);
  cvt_f32_f16<<<1024, 256, 0, stream>>>(wv, wvh, 1048576 / 4);
  cvt_f32_f16<<<1024, 256, 0, stream>>>(wo, woh, 1048576 / 4);

  proj_qk<<<dim3(128, 8, 2), 256, 0, stream>>>(xh, xl, wqh, wkh, bq, bk, Qfb, Kfb);
  proj_v<<<dim3(128, 8), 256, 0, stream>>>(xh, wvh, bv, Vtb);
  attn_kernel<<<dim3(8, 256), 256, 0, stream>>>(Qfb, Kfb, Vtb, Ofb);
  out_gemm<<<dim3(128, 8), 256, 0, stream>>>(Ofb, woh, bo, out);
}

// Round 5
// 411.270 us; speedup vs baseline: 1.5866x; 1.1745x over previous
//
#include <hip/hip_runtime.h>
#include <stdint.h>

typedef unsigned short u16;
typedef _Float16 f16;
typedef __attribute__((ext_vector_type(8))) _Float16 f16x8;
typedef __attribute__((ext_vector_type(4))) float f32x4;

__device__ __forceinline__ float exp2fast(float x) {
  return __builtin_amdgcn_exp2f(x);   // v_exp_f32: 2^x
}

__device__ __forceinline__ f32x4 mfma16(f16x8 a, f16x8 b, f32x4 c) {
  return __builtin_amdgcn_mfma_f32_16x16x32_f16(a, b, c, 0, 0, 0);
}

__device__ __forceinline__ u16 f2h(float f) {
  return __builtin_bit_cast(u16, (f16)f);
}

__device__ __forceinline__ void gld16(const void* g, void* l) {
  __builtin_amdgcn_global_load_lds(
      (const __attribute__((address_space(1))) unsigned int*)g,
      (__attribute__((address_space(3))) unsigned int*)l,
      16, 0, 0);
}

// ---------------- fp32 -> fp16 (plain) ----------------
__global__ __launch_bounds__(256) void cvt_f32_f16(const float* __restrict__ in,
                                                   u16* __restrict__ out, int n4) {
  int stride = gridDim.x * blockDim.x;
  for (int i = blockIdx.x * blockDim.x + threadIdx.x; i < n4; i += stride) {
    float4 v = reinterpret_cast<const float4*>(in)[i];
    ushort4 o;
    o.x = f2h(v.x); o.y = f2h(v.y); o.z = f2h(v.z); o.w = f2h(v.w);
    reinterpret_cast<ushort4*>(out)[i] = o;
  }
}

// stage one 128x32 tile (row-major, K=1024 source) into linear LDS
__device__ __forceinline__ void stage_tile(const u16* __restrict__ M, int r0, int k0,
                                           u16* S, int wid, int lane) {
#pragma unroll
  for (int it = 0; it < 2; ++it) {
    int row = wid * 32 + it * 16 + (lane >> 2);
    int col = k0 + (lane & 3) * 8;
    gld16(M + (size_t)(r0 + row) * 1024 + col, S + wid * 1024 + it * 512);
  }
}

// ---------------- unified Q/K/V projection (single-pass fp16) ----------------
// C[R][e] = sum_k x[R][k]*w[e][k] + bias[e]; scatter per-mat:
//   mat0: Q [b][h][m][j] scaled by 8*log2(e);  mat1: K [b][h][m][j];
//   mat2: Vt [b][h][j][m]
__global__ __launch_bounds__(256) void proj_qkv(
    const u16* __restrict__ xb,
    const u16* __restrict__ wqh, const u16* __restrict__ wkh, const u16* __restrict__ wvh,
    const float* __restrict__ bq, const float* __restrict__ bk, const float* __restrict__ bv,
    u16* __restrict__ Qf, u16* __restrict__ Kf, u16* __restrict__ Vt) {
  const int mat = blockIdx.z;
  const u16* __restrict__ w = (mat == 0) ? wqh : (mat == 1) ? wkh : wvh;
  const float* __restrict__ bias = (mat == 0) ? bq : (mat == 1) ? bk : bv;
  const int m0 = blockIdx.x * 128;
  const int n0 = blockIdx.y * 128;

  __shared__ __align__(16) u16 As[128 * 32];
  __shared__ __align__(16) u16 Bs[128 * 32];

  const int tid = threadIdx.x;
  const int lane = tid & 63;
  const int wid = tid >> 6;
  const int wr = wid >> 1, wc = wid & 1;
  const int qd = lane >> 4, lm = lane & 15;

  f32x4 acc[4][4];
#pragma unroll
  for (int i = 0; i < 4; ++i)
#pragma unroll
    for (int j = 0; j < 4; ++j) acc[i][j] = (f32x4){0.f, 0.f, 0.f, 0.f};

  stage_tile(xb, m0, 0, As, wid, lane);
  stage_tile(w, n0, 0, Bs, wid, lane);

  for (int kt = 0; kt < 32; ++kt) {
    __syncthreads();
    f16x8 af[4], bf[4];
#pragma unroll
    for (int i = 0; i < 4; ++i)
      af[i] = *reinterpret_cast<const f16x8*>(As + (wr * 64 + i * 16 + lm) * 32 + qd * 8);
#pragma unroll
    for (int j = 0; j < 4; ++j)
      bf[j] = *reinterpret_cast<const f16x8*>(Bs + (wc * 64 + j * 16 + lm) * 32 + qd * 8);
#pragma unroll
    for (int i = 0; i < 4; ++i)
#pragma unroll
      for (int j = 0; j < 4; ++j)
        acc[i][j] = mfma16(af[i], bf[j], acc[i][j]);
    __syncthreads();
    if (kt + 1 < 32) {
      stage_tile(xb, m0, (kt + 1) * 32, As, wid, lane);
      stage_tile(w, n0, (kt + 1) * 32, Bs, wid, lane);
    }
  }

  const float scale = (mat == 0) ? 11.5415603f : 1.0f;  // 8*log2(e) folded into Q
#pragma unroll
  for (int i = 0; i < 4; ++i) {
#pragma unroll
    for (int r = 0; r < 4; ++r) {
      int R = m0 + wr * 64 + i * 16 + qd * 4 + r;
      int bb = R >> 12, n = R & 4095;
      int c = n >> 10, s = n & 1023;
      int rb = s & 3, t = s >> 2;
      int m = c * 256 + t;
#pragma unroll
      for (int j = 0; j < 4; ++j) {
        int e = n0 + wc * 64 + j * 16 + lm;
        int head = e >> 6, jj = e & 63;
        int h = rb * 16 + head;
        float val = (acc[i][j][r] + bias[e]) * scale;
        u16 hv = f2h(val);
        if (mat == 2) {
          Vt[(((size_t)bb * 64 + h) * 64 + jj) * 1024 + m] = hv;
        } else {
          size_t idx = (((size_t)bb * 64 + h) * 1024 + m) * 64 + jj;
          if (mat == 0) Qf[idx] = hv;
          else          Kf[idx] = hv;
        }
      }
    }
  }
}

// swizzled LDS fragment read: row-major [64][64] fp16, 16B-granule XOR swizzle
__device__ __forceinline__ f16x8 lds_frag(const u16* base, int row, int blk) {
  return *reinterpret_cast<const f16x8*>(base + row * 64 + ((blk ^ (row & 7)) << 3));
}

// stage 64x64 fp16 K chunk + V chunk into swizzled LDS via global_load_lds
__device__ __forceinline__ void stage_kv(const u16* __restrict__ Kh,
                                         const u16* __restrict__ Vh, int kc,
                                         u16* KsB, u16* VsB, int wv, int lane) {
  const int l8 = lane >> 3, sl = lane & 7;
  const int rb = wv * 16;
#pragma unroll
  for (int it = 0; it < 2; ++it) {
    int row = rb + it * 8 + l8;
    int gsl = sl ^ l8;  // inverse-swizzled global granule
    gld16(Kh + (size_t)(kc * 64 + row) * 64 + gsl * 8, KsB + (rb + it * 8) * 64);
    gld16(Vh + (size_t)row * 1024 + kc * 64 + gsl * 8, VsB + (rb + it * 8) * 64);
  }
}

// ---------------- flash attention, swapped-QK, in-register P, defer-max ----------
__global__ __launch_bounds__(256) void attn_kernel(
    const u16* __restrict__ Qf, const u16* __restrict__ Kf,
    const u16* __restrict__ Vt, u16* __restrict__ Of) {
  // XCD-bijective swizzle: 8 m-chunks of one bh land on one XCD, adjacent in dispatch
  const int wgid = (blockIdx.x & 7) * 256 + (blockIdx.x >> 3);
  const int bh = wgid >> 3;
  const int m0 = (wgid & 7) * 128;
  const int b = bh >> 6, h = bh & 63;
  const int tid = threadIdx.x, lane = tid & 63, wv = tid >> 6;
  const int qd = lane >> 4, lm = lane & 15;

  __shared__ __align__(16) u16 Ks[2][64 * 64];
  __shared__ __align__(16) u16 Vs[2][64 * 64];

  const size_t hb = (size_t)(b * 64 + h);
  const u16* __restrict__ Qh = Qf + hb * 65536;
  const u16* __restrict__ Kh = Kf + hb * 65536;
  const u16* __restrict__ Vh = Vt + hb * 65536;

  // Q fragments (B-operand: q-row = lm)
  f16x8 qf[2][2];
#pragma unroll
  for (int im = 0; im < 2; ++im)
#pragma unroll
    for (int ks = 0; ks < 2; ++ks)
      qf[im][ks] = *reinterpret_cast<const f16x8*>(
          Qh + (size_t)(m0 + wv * 32 + im * 16 + lm) * 64 + ks * 32 + qd * 8);

  f32x4 oa[2][4];
  float mrow[2] = {-1e30f, -1e30f};
  float lrow[2] = {0.f, 0.f};
#pragma unroll
  for (int im = 0; im < 2; ++im)
#pragma unroll
    for (int jf = 0; jf < 4; ++jf) oa[im][jf] = (f32x4){0.f, 0.f, 0.f, 0.f};

  stage_kv(Kh, Vh, 0, &Ks[0][0], &Vs[0][0], wv, lane);

  for (int kc = 0; kc < 16; ++kc) {
    const int buf = kc & 1;
    __syncthreads();  // drains staging of buf
    if (kc + 1 < 16) stage_kv(Kh, Vh, kc + 1, &Ks[buf ^ 1][0], &Vs[buf ^ 1][0], wv, lane);

    // swapped QK^T: sc[im][nf] rows = k-local (16nf+4qd+r), cols = q (lm)
    f32x4 sc[2][4];
#pragma unroll
    for (int im = 0; im < 2; ++im)
#pragma unroll
      for (int nf = 0; nf < 4; ++nf) sc[im][nf] = (f32x4){0.f, 0.f, 0.f, 0.f};
#pragma unroll
    for (int ks = 0; ks < 2; ++ks) {
      f16x8 kfr[4];
#pragma unroll
      for (int nf = 0; nf < 4; ++nf)
        kfr[nf] = lds_frag(&Ks[buf][0], nf * 16 + lm, ks * 4 + qd);
#pragma unroll
      for (int im = 0; im < 2; ++im)
#pragma unroll
        for (int nf = 0; nf < 4; ++nf)
          sc[im][nf] = mfma16(kfr[nf], qf[im][ks], sc[im][nf]);
    }

    // online softmax (log2 domain), defer-max with THR=8: P bounded by 2^8
    unsigned int pk[2][8];
#pragma unroll
    for (int im = 0; im < 2; ++im) {
      float pm = sc[im][0][0];
#pragma unroll
      for (int nf = 0; nf < 4; ++nf)
#pragma unroll
        for (int r = 0; r < 4; ++r) pm = fmaxf(pm, sc[im][nf][r]);
      pm = fmaxf(pm, __shfl_xor(pm, 16));
      pm = fmaxf(pm, __shfl_xor(pm, 32));
      if (__all(pm <= mrow[im] + 8.0f)) {
        // defer: keep old max, no O-rescale
        float mn = mrow[im];
        float s = 0.f;
#pragma unroll
        for (int nf = 0; nf < 4; ++nf) {
          float p0 = exp2fast(sc[im][nf][0] - mn);
          float p1 = exp2fast(sc[im][nf][1] - mn);
          float p2 = exp2fast(sc[im][nf][2] - mn);
          float p3 = exp2fast(sc[im][nf][3] - mn);
          s += (p0 + p1) + (p2 + p3);
          pk[im][2 * nf + 0] = __builtin_bit_cast(unsigned int, __builtin_amdgcn_cvt_pkrtz(p0, p1));
          pk[im][2 * nf + 1] = __builtin_bit_cast(unsigned int, __builtin_amdgcn_cvt_pkrtz(p2, p3));
        }
        s += __shfl_xor(s, 16);
        s += __shfl_xor(s, 32);
        lrow[im] += s;
      } else {
        float mn = fmaxf(mrow[im], pm);
        float corr = exp2fast(mrow[im] - mn);
        mrow[im] = mn;
        float s = 0.f;
#pragma unroll
        for (int nf = 0; nf < 4; ++nf) {
          float p0 = exp2fast(sc[im][nf][0] - mn);
          float p1 = exp2fast(sc[im][nf][1] - mn);
          float p2 = exp2fast(sc[im][nf][2] - mn);
          float p3 = exp2fast(sc[im][nf][3] - mn);
          s += (p0 + p1) + (p2 + p3);
          pk[im][2 * nf + 0] = __builtin_bit_cast(unsigned int, __builtin_amdgcn_cvt_pkrtz(p0, p1));
          pk[im][2 * nf + 1] = __builtin_bit_cast(unsigned int, __builtin_amdgcn_cvt_pkrtz(p2, p3));
        }
        s += __shfl_xor(s, 16);
        s += __shfl_xor(s, 32);
        lrow[im] = lrow[im] * corr + s;
        // rescale O by corr (broadcast per accumulator row)
#pragma unroll
        for (int r = 0; r < 4; ++r) {
          float cb = __shfl(corr, qd * 4 + r);
#pragma unroll
          for (int jf = 0; jf < 4; ++jf) oa[im][jf][r] *= cb;
        }
      }
    }

    // PV: redistribute P to A-fragment layout via shfl, then MFMA
#pragma unroll
    for (int ks = 0; ks < 2; ++ks) {
      f16x8 vfr[4];
#pragma unroll
      for (int jf = 0; jf < 4; ++jf)
        vfr[jf] = lds_frag(&Vs[buf][0], jf * 16 + lm, ks * 4 + qd);
#pragma unroll
      for (int im = 0; im < 2; ++im) {
        union { unsigned int w[4]; f16x8 hv; } pa;
#pragma unroll
        for (int w = 0; w < 4; ++w) {
          int srcl = (((2 * qd + (w >> 1)) & 3) << 4) + lm;
          unsigned int a0 = __shfl(pk[im][2 * (2 * ks + 0) + (w & 1)], srcl);
          unsigned int a1 = __shfl(pk[im][2 * (2 * ks + 1) + (w & 1)], srcl);
          pa.w[w] = (qd & 2) ? a1 : a0;
        }
#pragma unroll
        for (int jf = 0; jf < 4; ++jf)
          oa[im][jf] = mfma16(pa.hv, vfr[jf], oa[im][jf]);
      }
    }
  }

  // epilogue: normalize, scatter to Of[b][n][f] (fp16)
  const int rb = h >> 4, head = h & 15;
#pragma unroll
  for (int im = 0; im < 2; ++im) {
#pragma unroll
    for (int r = 0; r < 4; ++r) {
      float lb = __shfl(lrow[im], qd * 4 + r);
      float inv = 1.0f / lb;
      int mq = m0 + wv * 32 + im * 16 + qd * 4 + r;
      int c = mq >> 8, t = mq & 255;
      int s = t * 4 + rb;
      int n = c * 1024 + s;
#pragma unroll
      for (int jf = 0; jf < 4; ++jf) {
        int j = jf * 16 + lm;
        int f = head * 64 + j;
        Of[((size_t)b * 4096 + n) * 1024 + f] = f2h(oa[im][jf][r] * inv);
      }
    }
  }
}

// ---------------- output projection GEMM (fp16 single-pass) ----------------
__global__ __launch_bounds__(256) void out_gemm(
    const u16* __restrict__ Of, const u16* __restrict__ woh,
    const float* __restrict__ bo, float* __restrict__ out) {
  const int m0 = blockIdx.x * 128;
  const int n0 = blockIdx.y * 128;

  __shared__ __align__(16) u16 As[128 * 32];
  __shared__ __align__(16) u16 Bs[128 * 32];

  const int tid = threadIdx.x;
  const int lane = tid & 63;
  const int wid = tid >> 6;
  const int wr = wid >> 1, wc = wid & 1;
  const int qd = lane >> 4, lm = lane & 15;

  f32x4 acc[4][4];
#pragma unroll
  for (int i = 0; i < 4; ++i)
#pragma unroll
    for (int j = 0; j < 4; ++j) acc[i][j] = (f32x4){0.f, 0.f, 0.f, 0.f};

  stage_tile(Of, m0, 0, As, wid, lane);
  stage_tile(woh, n0, 0, Bs, wid, lane);

  for (int kt = 0; kt < 32; ++kt) {
    __syncthreads();
    f16x8 af[4], bf[4];
#pragma unroll
    for (int i = 0; i < 4; ++i)
      af[i] = *reinterpret_cast<const f16x8*>(As + (wr * 64 + i * 16 + lm) * 32 + qd * 8);
#pragma unroll
    for (int j = 0; j < 4; ++j)
      bf[j] = *reinterpret_cast<const f16x8*>(Bs + (wc * 64 + j * 16 + lm) * 32 + qd * 8);
#pragma unroll
    for (int i = 0; i < 4; ++i)
#pragma unroll
      for (int j = 0; j < 4; ++j)
        acc[i][j] = mfma16(af[i], bf[j], acc[i][j]);
    __syncthreads();
    if (kt + 1 < 32) {
      stage_tile(Of, m0, (kt + 1) * 32, As, wid, lane);
      stage_tile(woh, n0, (kt + 1) * 32, Bs, wid, lane);
    }
  }

#pragma unroll
  for (int i = 0; i < 4; ++i) {
#pragma unroll
    for (int r = 0; r < 4; ++r) {
      int R = m0 + wr * 64 + i * 16 + qd * 4 + r;
#pragma unroll
      for (int j = 0; j < 4; ++j) {
        int e = n0 + wc * 64 + j * 16 + lm;
        out[(size_t)R * 1024 + e] = acc[i][j][r] + bo[e];
      }
    }
  }
}

// ---------------- launch ----------------
extern "C" void kernel_launch(void* const* d_in, const int* in_sizes, int n_in,
                              void* d_out, int out_size, void* d_ws, size_t ws_size,
                              hipStream_t stream) {
  const float* x  = (const float*)d_in[0];
  const float* wq = (const float*)d_in[1];
  const float* bq = (const float*)d_in[2];
  const float* wk = (const float*)d_in[3];
  const float* bk = (const float*)d_in[4];
  const float* wv = (const float*)d_in[5];
  const float* bv = (const float*)d_in[6];
  const float* wo = (const float*)d_in[7];
  const float* bo = (const float*)d_in[8];
  float* out = (float*)d_out;

  char* ws = (char*)d_ws;
  u16* xb  = (u16*)(ws + 0);            // 33,554,432 B
  u16* wqh = (u16*)(ws + 33554432);     //  2,097,152 B each
  u16* wkh = (u16*)(ws + 35651584);
  u16* wvh = (u16*)(ws + 37748736);
  u16* woh = (u16*)(ws + 39845888);
  u16* Qfb = (u16*)(ws + 41943040);     // 33,554,432 B  [b][h][m][j] (pre-scaled)
  u16* Kfb = (u16*)(ws + 75497472);     // 33,554,432 B  [b][h][m][j]
  u16* Vtb = (u16*)(ws + 109051904);    // 33,554,432 B  [b][h][j][m]
  u16* Ofb = (u16*)(ws + 142606336);    // 33,554,432 B  [b][n][f]

  cvt_f32_f16<<<4096, 256, 0, stream>>>(x,  xb,  16777216 / 4);
  cvt_f32_f16<<<1024, 256, 0, stream>>>(wq, wqh, 1048576 / 4);
  cvt_f32_f16<<<1024, 256, 0, stream>>>(wk, wkh, 1048576 / 4);
  cvt_f32_f16<<<1024, 256, 0, stream>>>(wv, wvh, 1048576 / 4);
  cvt_f32_f16<<<1024, 256, 0, stream>>>(wo, woh, 1048576 / 4);

  proj_qkv<<<dim3(128, 8, 3), 256, 0, stream>>>(xb, wqh, wkh, wvh, bq, bk, bv,
                                                Qfb, Kfb, Vtb);
  attn_kernel<<<2048, 256, 0, stream>>>(Qfb, Kfb, Vtb, Ofb);
  out_gemm<<<dim3(128, 8), 256, 0, stream>>>(Ofb, woh, bo, out);
}